// Round 13
// baseline (219.779 us; speedup 1.0000x reference)
//
#include <hip/hip_runtime.h>
#include <math.h>

#define NN 50000
#define EE 800000
#define DIN 128
#define HH 256
#define CC 47
#define LK2 264     // LDS row stride in bf16 (256 + 8 pad)
#define GS_BLOCKS 2048
#define LOSS_BLOCKS 2048
#define EDGE_CH 4096
#define EDGE_NCH ((EE + EDGE_CH - 1) / EDGE_CH)   // 196
#define EDGE_BLOCKS (EDGE_NCH * 8)                // 1568
#define OTHER_BLOCKS ((NN * 32 + 255) / 256)      // 6250

typedef short bf16x8 __attribute__((ext_vector_type(8)));
typedef float f32x4 __attribute__((ext_vector_type(4)));
typedef float f32x2 __attribute__((ext_vector_type(2)));

static __device__ __forceinline__ unsigned short f2bf(float f) {
    unsigned u = __float_as_uint(f);
    u = u + 0x7fff + ((u >> 16) & 1);
    return (unsigned short)(u >> 16);
}

// -- fused prep (R9 plain form; NT variants falsified R5/R12 — parked)
__global__ __launch_bounds__(256) void prep_kernel(
    const float* __restrict__ x, const int* __restrict__ row,
    const int* __restrict__ col, const int* __restrict__ msk,
    const float* __restrict__ w1n, const float* __restrict__ w1s,
    const float* __restrict__ b1n, const float* __restrict__ b1s,
    const float* __restrict__ w2n, const float* __restrict__ w2s,
    int* __restrict__ cnt, unsigned short* __restrict__ bucket,
    unsigned* __restrict__ xq, unsigned* __restrict__ ab,
    unsigned short* __restrict__ WB1, unsigned short* __restrict__ WB2,
    float* __restrict__ bias1, unsigned* __restrict__ znq,
    int* __restrict__ mcount, int* __restrict__ mlist)
{
    if (blockIdx.x < EDGE_BLOCKS) {
        const int xcd = blockIdx.x & 7;
        const int base = (blockIdx.x >> 3) * EDGE_CH;
        for (int k = threadIdx.x; k < EDGE_CH; k += 256) {
            int e = base + k;
            if (e < EE) {
                int r = row[e];
                if ((r & 7) == xcd) {
                    int pos = atomicAdd(&cnt[r], 1);
                    if (pos < 64) bucket[r * 64 + pos] = (unsigned short)col[e];
                }
            }
        }
        return;
    }
    int t = (blockIdx.x - EDGE_BLOCKS) * 256 + threadIdx.x;
    if (t < NN) {
        *(uint4*)&znq[(size_t)t * 16 + 12] = make_uint4(0u, 0u, 0u, 0u);
        int m = msk[t] ? 1 : 0;
        unsigned long long b = __ballot(m);
        int lane = threadIdx.x & 63;
        int prefix = __popcll(b & ((1ull << lane) - 1ull));
        int tot = __popcll(b);
        int base_ = 0;
        if (lane == 0 && tot) base_ = atomicAdd(mcount, tot);
        base_ = __shfl(base_, 0);
        if (m) mlist[base_ + prefix] = t;
    }
    if (t < NN * 32) {
        int i = t >> 5, c = t & 31;
        float4 v = *(const float4*)&x[(size_t)i * DIN + c * 4];
        int p = __builtin_amdgcn_cvt_pk_fp8_f32(v.x, v.y, 0, false);
        p = __builtin_amdgcn_cvt_pk_fp8_f32(v.z, v.w, p, true);
        xq[(size_t)i * 32 + c] = (unsigned)p;
        ab[(size_t)i * 128 + 64 + 2 * c]     = (unsigned)f2bf(v.x) | ((unsigned)f2bf(v.y) << 16);
        ab[(size_t)i * 128 + 64 + 2 * c + 1] = (unsigned)f2bf(v.z) | ((unsigned)f2bf(v.w) << 16);
    }
    if (t < 65536) {
        int k = t >> 8, n = t & 255;
        float v = (k < 128) ? w1n[k * HH + n] : w1s[(k - 128) * HH + n];
        WB1[n * 256 + k] = f2bf(v);
    } else if (t < 65536 + 24576) {
        int q = t - 65536;
        int k = q / 96, n = q % 96;
        float v;
        if (n < 48) v = (n < CC) ? w2n[k * CC + n] : 0.f;
        else { int m2 = n - 48; v = (m2 < CC) ? w2s[k * CC + m2] : 0.f; }
        WB2[n * 256 + k] = f2bf(v);
    } else if (t < 65536 + 24576 + 256) {
        int n = t - 65536 - 24576;
        bias1[n] = b1n[n] + b1s[n];
    }
}

// ----------------------------------------------- layer-1 gather (fp8 x)
__global__ __launch_bounds__(256) void agg1(const unsigned* __restrict__ xq,
                                            const int* __restrict__ cnt,
                                            const unsigned short* __restrict__ bucket,
                                            unsigned* __restrict__ ab) {
    int wave = threadIdx.x >> 6, lane = threadIdx.x & 63;
    const int h = lane >> 5, hl = lane & 31;
    const int W = gridDim.x * 4;
    for (int i = blockIdx.x * 4 + wave; i < NN; i += W) {
        int e = cnt[i];
        float dvs = fmaxf((float)e, 1.0f);
        if (e > 64) e = 64;
        float A0=0,A1=0,A2=0,A3=0, B0=0,B1=0,B2=0,B3=0;
        float C0=0,C1=0,C2=0,C3=0, D0=0,D1=0,D2=0,D3=0;
        if (e > 0) {
            int myidx = bucket[i * 64 + min(lane, e - 1)];
            int j = 0;
            for (; j + 16 <= e; j += 16) {
                int n0 = __shfl(myidx, j + h);
                int n1 = __shfl(myidx, j + 2 + h);
                int n2 = __shfl(myidx, j + 4 + h);
                int n3 = __shfl(myidx, j + 6 + h);
                int n4 = __shfl(myidx, j + 8 + h);
                int n5 = __shfl(myidx, j + 10 + h);
                int n6 = __shfl(myidx, j + 12 + h);
                int n7 = __shfl(myidx, j + 14 + h);
                unsigned u0 = xq[(size_t)n0 * 32 + hl];
                unsigned u1 = xq[(size_t)n1 * 32 + hl];
                unsigned u2 = xq[(size_t)n2 * 32 + hl];
                unsigned u3 = xq[(size_t)n3 * 32 + hl];
                unsigned u4 = xq[(size_t)n4 * 32 + hl];
                unsigned u5 = xq[(size_t)n5 * 32 + hl];
                unsigned u6 = xq[(size_t)n6 * 32 + hl];
                unsigned u7 = xq[(size_t)n7 * 32 + hl];
                f32x2 l0 = __builtin_amdgcn_cvt_pk_f32_fp8(u0, false);
                f32x2 h0 = __builtin_amdgcn_cvt_pk_f32_fp8(u0, true);
                f32x2 l1 = __builtin_amdgcn_cvt_pk_f32_fp8(u1, false);
                f32x2 h1 = __builtin_amdgcn_cvt_pk_f32_fp8(u1, true);
                f32x2 l2 = __builtin_amdgcn_cvt_pk_f32_fp8(u2, false);
                f32x2 h2 = __builtin_amdgcn_cvt_pk_f32_fp8(u2, true);
                f32x2 l3 = __builtin_amdgcn_cvt_pk_f32_fp8(u3, false);
                f32x2 h3 = __builtin_amdgcn_cvt_pk_f32_fp8(u3, true);
                A0 += l0.x; A1 += l0.y; A2 += h0.x; A3 += h0.y;
                B0 += l1.x; B1 += l1.y; B2 += h1.x; B3 += h1.y;
                C0 += l2.x; C1 += l2.y; C2 += h2.x; C3 += h2.y;
                D0 += l3.x; D1 += l3.y; D2 += h3.x; D3 += h3.y;
                f32x2 l4 = __builtin_amdgcn_cvt_pk_f32_fp8(u4, false);
                f32x2 h4 = __builtin_amdgcn_cvt_pk_f32_fp8(u4, true);
                f32x2 l5 = __builtin_amdgcn_cvt_pk_f32_fp8(u5, false);
                f32x2 h5 = __builtin_amdgcn_cvt_pk_f32_fp8(u5, true);
                f32x2 l6 = __builtin_amdgcn_cvt_pk_f32_fp8(u6, false);
                f32x2 h6 = __builtin_amdgcn_cvt_pk_f32_fp8(u6, true);
                f32x2 l7 = __builtin_amdgcn_cvt_pk_f32_fp8(u7, false);
                f32x2 h7 = __builtin_amdgcn_cvt_pk_f32_fp8(u7, true);
                A0 += l4.x; A1 += l4.y; A2 += h4.x; A3 += h4.y;
                B0 += l5.x; B1 += l5.y; B2 += h5.x; B3 += h5.y;
                C0 += l6.x; C1 += l6.y; C2 += h6.x; C3 += h6.y;
                D0 += l7.x; D1 += l7.y; D2 += h7.x; D3 += h7.y;
            }
            for (; j + 8 <= e; j += 8) {
                int n0 = __shfl(myidx, j + h);
                int n1 = __shfl(myidx, j + 2 + h);
                int n2 = __shfl(myidx, j + 4 + h);
                int n3 = __shfl(myidx, j + 6 + h);
                unsigned u0 = xq[(size_t)n0 * 32 + hl];
                unsigned u1 = xq[(size_t)n1 * 32 + hl];
                unsigned u2 = xq[(size_t)n2 * 32 + hl];
                unsigned u3 = xq[(size_t)n3 * 32 + hl];
                f32x2 l0 = __builtin_amdgcn_cvt_pk_f32_fp8(u0, false);
                f32x2 h0 = __builtin_amdgcn_cvt_pk_f32_fp8(u0, true);
                f32x2 l1 = __builtin_amdgcn_cvt_pk_f32_fp8(u1, false);
                f32x2 h1 = __builtin_amdgcn_cvt_pk_f32_fp8(u1, true);
                f32x2 l2 = __builtin_amdgcn_cvt_pk_f32_fp8(u2, false);
                f32x2 h2 = __builtin_amdgcn_cvt_pk_f32_fp8(u2, true);
                f32x2 l3 = __builtin_amdgcn_cvt_pk_f32_fp8(u3, false);
                f32x2 h3 = __builtin_amdgcn_cvt_pk_f32_fp8(u3, true);
                A0 += l0.x; A1 += l0.y; A2 += h0.x; A3 += h0.y;
                B0 += l1.x; B1 += l1.y; B2 += h1.x; B3 += h1.y;
                C0 += l2.x; C1 += l2.y; C2 += h2.x; C3 += h2.y;
                D0 += l3.x; D1 += l3.y; D2 += h3.x; D3 += h3.y;
            }
            for (; j < e; j += 2) {
                int src = j + h;
                int n = __shfl(myidx, min(src, e - 1));
                unsigned u = xq[(size_t)n * 32 + hl];
                if (src >= e) u = 0u;
                f32x2 lo = __builtin_amdgcn_cvt_pk_f32_fp8(u, false);
                f32x2 hi = __builtin_amdgcn_cvt_pk_f32_fp8(u, true);
                A0 += lo.x; A1 += lo.y; A2 += hi.x; A3 += hi.y;
            }
        }
        float s0 = (A0 + B0) + (C0 + D0);
        float s1 = (A1 + B1) + (C1 + D1);
        float s2 = (A2 + B2) + (C2 + D2);
        float s3 = (A3 + B3) + (C3 + D3);
        s0 += __shfl_xor(s0, 32); s1 += __shfl_xor(s1, 32);
        s2 += __shfl_xor(s2, 32); s3 += __shfl_xor(s3, 32);
        if (h == 0) {
            float sc = 1.0f / dvs;
            unsigned d0 = (unsigned)f2bf(s0 * sc) | ((unsigned)f2bf(s1 * sc) << 16);
            unsigned d1 = (unsigned)f2bf(s2 * sc) | ((unsigned)f2bf(s3 * sc) << 16);
            *(uint2*)&ab[(size_t)i * 128 + 2 * hl] = make_uint2(d0, d1);
        }
    }
}

// layer-2 epilogue helper (c<48 branch is wave-uniform per 16-col group)
static __device__ __forceinline__ void epi_row(
    f32x4 acc, int c, int gi_base, int l16,
    unsigned* __restrict__ znq, float* __restrict__ zsb,
    const float* __restrict__ b2n, const float* __restrict__ b2s)
{
    if (c < 48) {
#pragma unroll
        for (int r = 0; r < 4; ++r) {
            float v = acc[r];
            float v1 = __shfl_down(v, 1);
            float v2 = __shfl_down(v, 2);
            float v3 = __shfl_down(v, 3);
            int gi = gi_base + r;
            if (((l16 & 3) == 0) && gi < NN) {
                int pk = __builtin_amdgcn_cvt_pk_fp8_f32(v, v1, 0, false);
                pk = __builtin_amdgcn_cvt_pk_fp8_f32(v2, v3, pk, true);
                znq[(size_t)gi * 16 + (c >> 2)] = (unsigned)pk;
            }
        }
    } else {
        int cz = c - 48;
        float bias = (cz < CC) ? (b2n[cz] + b2s[cz]) : 0.f;
#pragma unroll
        for (int r = 0; r < 4; ++r) {
            int gi = gi_base + r;
            if (gi < NN) zsb[(size_t)gi * 48 + cz] = acc[r] + bias;
        }
    }
}

// ------------------- FUSED layer-1 + layer-2 GEMM v5: COLUMN-SPLIT
// 64 rows/block. Each wave owns a COLUMN range: A for all 64 rows in regs
// (128 VGPR; 4x global re-read absorbed by shared L1), B per wave is
// DISTINCT -> global->reg with 2-deep register double-buffer (the prefetch
// distance R10 lacked). Layer-1 barrier-free; ONE barrier assembles h in
// LDS; layer-2 reads h-frags once into recycled A regs. LDS/block 33.8KB;
// per-block LDS traffic ~160KB vs ~924KB in the row-split dbuf version.
__global__ __launch_bounds__(256) void gemm12_fused(
    const unsigned short* __restrict__ AB,
    const unsigned short* __restrict__ WB1, const unsigned short* __restrict__ WB2,
    const float* __restrict__ bias1,
    const float* __restrict__ b2n, const float* __restrict__ b2s,
    unsigned* __restrict__ znq, float* __restrict__ zsb)
{
    __shared__ unsigned short sH[64 * LK2];
    const int tid = threadIdx.x;
    const int i0 = blockIdx.x * 64;
    const int wv = tid >> 6, lane = tid & 63;
    const int g = lane >> 4, l16 = lane & 15;
    const int colw = wv * 64;           // wave's layer-1 column base

    // ---- A: all 64 rows -> regs (4 row-tiles x 8 ks x bf16x8 per lane)
    bf16x8 areg[4][8];
#pragma unroll
    for (int rt = 0; rt < 4; ++rt) {
        int arow = i0 + rt * 16 + l16;
#pragma unroll
        for (int ks = 0; ks < 8; ++ks) {
            bf16x8 v = {};
            if (arow < NN) v = *(const bf16x8*)&AB[(size_t)arow * 256 + ks * 32 + g * 8];
            areg[rt][ks] = v;
        }
    }

    // ---- layer 1: 4 col-groups of 16 per wave, B global->reg dbuf, no barriers
    bf16x8 b0[8], b1[8];
#pragma unroll
    for (int ks = 0; ks < 8; ++ks)
        b0[ks] = *(const bf16x8*)&WB1[(size_t)(colw + l16) * 256 + ks * 32 + g * 8];
#pragma unroll
    for (int cgi = 0; cgi < 4; ++cgi) {
        if (cgi < 3) {
#pragma unroll
            for (int ks = 0; ks < 8; ++ks)
                b1[ks] = *(const bf16x8*)&WB1[(size_t)(colw + (cgi + 1) * 16 + l16) * 256 + ks * 32 + g * 8];
        }
        f32x4 a0 = {}, a1 = {}, a2 = {}, a3 = {};
#pragma unroll
        for (int ks = 0; ks < 8; ++ks) {
            a0 = __builtin_amdgcn_mfma_f32_16x16x32_bf16(areg[0][ks], b0[ks], a0, 0, 0, 0);
            a1 = __builtin_amdgcn_mfma_f32_16x16x32_bf16(areg[1][ks], b0[ks], a1, 0, 0, 0);
            a2 = __builtin_amdgcn_mfma_f32_16x16x32_bf16(areg[2][ks], b0[ks], a2, 0, 0, 0);
            a3 = __builtin_amdgcn_mfma_f32_16x16x32_bf16(areg[3][ks], b0[ks], a3, 0, 0, 0);
        }
        int colh = colw + cgi * 16 + l16;
        float bi = bias1[colh];
#pragma unroll
        for (int r = 0; r < 4; ++r) {
            sH[(g * 4 + r) * LK2 + colh]        = f2bf(fmaxf(a0[r] + bi, 0.f));
            sH[(16 + g * 4 + r) * LK2 + colh]   = f2bf(fmaxf(a1[r] + bi, 0.f));
            sH[(32 + g * 4 + r) * LK2 + colh]   = f2bf(fmaxf(a2[r] + bi, 0.f));
            sH[(48 + g * 4 + r) * LK2 + colh]   = f2bf(fmaxf(a3[r] + bi, 0.f));
        }
        if (cgi < 3) {
#pragma unroll
            for (int ks = 0; ks < 8; ++ks) b0[ks] = b1[ks];
        }
    }
    __syncthreads();

    // ---- layer 2: groups over 96 cols: wave0 {0,1}, wave1 {2,3}, wave2 {4}, wave3 {5}
    const int ng = (wv < 2) ? 2 : 1;
    const int gbase = (wv < 2) ? wv * 2 : wv + 2;
    // issue B2 global loads FIRST (latency hides under the LDS h reads)
    bf16x8 b2a[8], b2b[8];
#pragma unroll
    for (int ks = 0; ks < 8; ++ks)
        b2a[ks] = *(const bf16x8*)&WB2[(size_t)(gbase * 16 + l16) * 256 + ks * 32 + g * 8];
    if (ng == 2) {
#pragma unroll
        for (int ks = 0; ks < 8; ++ks)
            b2b[ks] = *(const bf16x8*)&WB2[(size_t)((gbase + 1) * 16 + l16) * 256 + ks * 32 + g * 8];
    }
    // h fragments from LDS into the recycled A registers
#pragma unroll
    for (int rt = 0; rt < 4; ++rt)
#pragma unroll
        for (int ks = 0; ks < 8; ++ks)
            areg[rt][ks] = *(const bf16x8*)&sH[(rt * 16 + l16) * LK2 + ks * 32 + g * 8];

    {
        f32x4 a0 = {}, a1 = {}, a2 = {}, a3 = {};
#pragma unroll
        for (int ks = 0; ks < 8; ++ks) {
            a0 = __builtin_amdgcn_mfma_f32_16x16x32_bf16(areg[0][ks], b2a[ks], a0, 0, 0, 0);
            a1 = __builtin_amdgcn_mfma_f32_16x16x32_bf16(areg[1][ks], b2a[ks], a1, 0, 0, 0);
            a2 = __builtin_amdgcn_mfma_f32_16x16x32_bf16(areg[2][ks], b2a[ks], a2, 0, 0, 0);
            a3 = __builtin_amdgcn_mfma_f32_16x16x32_bf16(areg[3][ks], b2a[ks], a3, 0, 0, 0);
        }
        int c = gbase * 16 + l16;
        epi_row(a0, c, i0 +  0 + g * 4, l16, znq, zsb, b2n, b2s);
        epi_row(a1, c, i0 + 16 + g * 4, l16, znq, zsb, b2n, b2s);
        epi_row(a2, c, i0 + 32 + g * 4, l16, znq, zsb, b2n, b2s);
        epi_row(a3, c, i0 + 48 + g * 4, l16, znq, zsb, b2n, b2s);
    }
    if (ng == 2) {
        f32x4 a0 = {}, a1 = {}, a2 = {}, a3 = {};
#pragma unroll
        for (int ks = 0; ks < 8; ++ks) {
            a0 = __builtin_amdgcn_mfma_f32_16x16x32_bf16(areg[0][ks], b2b[ks], a0, 0, 0, 0);
            a1 = __builtin_amdgcn_mfma_f32_16x16x32_bf16(areg[1][ks], b2b[ks], a1, 0, 0, 0);
            a2 = __builtin_amdgcn_mfma_f32_16x16x32_bf16(areg[2][ks], b2b[ks], a2, 0, 0, 0);
            a3 = __builtin_amdgcn_mfma_f32_16x16x32_bf16(areg[3][ks], b2b[ks], a3, 0, 0, 0);
        }
        int c = (gbase + 1) * 16 + l16;
        epi_row(a0, c, i0 +  0 + g * 4, l16, znq, zsb, b2n, b2s);
        epi_row(a1, c, i0 + 16 + g * 4, l16, znq, zsb, b2n, b2s);
        epi_row(a2, c, i0 + 32 + g * 4, l16, znq, zsb, b2n, b2s);
        epi_row(a3, c, i0 + 48 + g * 4, l16, znq, zsb, b2n, b2s);
    }
}

// --------------- masked loss: mlist, fp8 znq, 2 nodes per half-wave concurrent,
// per-block partials via plain stores (no same-address atomics)
__global__ __launch_bounds__(256) void loss_kernel(
    const unsigned* __restrict__ znq, const float* __restrict__ zsb,
    const int* __restrict__ cnt, const unsigned short* __restrict__ bucket,
    const int* __restrict__ y, const int* __restrict__ mcount,
    const int* __restrict__ mlist, float* __restrict__ partials)
{
    __shared__ float red[16];
    const int tid = threadIdx.x;
    const int wave = tid >> 6, lane = tid & 63;
    const int half = lane >> 5, hl = lane & 31;
    const int h32 = lane & 32;
    const int eg = hl >> 4, dwl = hl & 15;
    const int HW = gridDim.x * 8;
    const int M = mcount[0];
    float num = 0.f, den = 0.f;

    for (int pa = ((blockIdx.x * 4 + wave) * 2 + half) * 2; pa < M; pa += 2 * HW) {
        int i0 = mlist[pa];
        bool v1 = (pa + 1 < M);
        int i1 = v1 ? mlist[pa + 1] : i0;
        int c0 = cnt[i0], c1 = cnt[i1];
        int e0 = min(c0, 64), e1 = min(c1, 64);
        int yi0 = y[i0], yi1 = y[i1];
        int mi0 = bucket[(size_t)i0 * 64 + min(hl, max(e0 - 1, 0))];
        int mi1 = bucket[(size_t)i1 * 64 + min(hl, max(e1 - 1, 0))];
        int dwm = min(dwl, 11);
        float4 zs0 = *(const float4*)&zsb[(size_t)i0 * 48 + 4 * dwm];
        float4 zs1 = *(const float4*)&zsb[(size_t)i1 * 48 + 4 * dwm];

        unsigned ua[16], ub[16];
#pragma unroll
        for (int q = 0; q < 16; ++q) {
            int n = __shfl(mi0, h32 + 2 * q + eg);
            ua[q] = znq[(size_t)n * 16 + dwl];
        }
#pragma unroll
        for (int q = 0; q < 16; ++q) {
            int n = __shfl(mi1, h32 + 2 * q + eg);
            ub[q] = znq[(size_t)n * 16 + dwl];
        }
        float a0=0.f,a1=0.f,a2=0.f,a3=0.f, b0=0.f,b1=0.f,b2=0.f,b3=0.f;
#pragma unroll
        for (int q = 0; q < 16; ++q) {
            int s = 2 * q + eg;
            unsigned u = (s < e0) ? ua[q] : 0u;
            f32x2 lo = __builtin_amdgcn_cvt_pk_f32_fp8(u, false);
            f32x2 hi = __builtin_amdgcn_cvt_pk_f32_fp8(u, true);
            a0 += lo.x; a1 += lo.y; a2 += hi.x; a3 += hi.y;
            unsigned w = (s < e1) ? ub[q] : 0u;
            f32x2 lo2 = __builtin_amdgcn_cvt_pk_f32_fp8(w, false);
            f32x2 hi2 = __builtin_amdgcn_cvt_pk_f32_fp8(w, true);
            b0 += lo2.x; b1 += lo2.y; b2 += hi2.x; b3 += hi2.y;
        }
        if (e0 > 32 || e1 > 32) {
            int mj0 = bucket[(size_t)i0 * 64 + min(32 + hl, max(e0 - 1, 0))];
            int mj1 = bucket[(size_t)i1 * 64 + min(32 + hl, max(e1 - 1, 0))];
            unsigned va[16], vb[16];
#pragma unroll
            for (int q = 0; q < 16; ++q) {
                int n = __shfl(mj0, h32 + 2 * q + eg);
                va[q] = znq[(size_t)n * 16 + dwl];
            }
#pragma unroll
            for (int q = 0; q < 16; ++q) {
                int n = __shfl(mj1, h32 + 2 * q + eg);
                vb[q] = znq[(size_t)n * 16 + dwl];
            }
#pragma unroll
            for (int q = 0; q < 16; ++q) {
                int s = 32 + 2 * q + eg;
                unsigned u = (s < e0) ? va[q] : 0u;
                f32x2 lo = __builtin_amdgcn_cvt_pk_f32_fp8(u, false);
                f32x2 hi = __builtin_amdgcn_cvt_pk_f32_fp8(u, true);
                a0 += lo.x; a1 += lo.y; a2 += hi.x; a3 += hi.y;
                unsigned w = (s < e1) ? vb[q] : 0u;
                f32x2 lo2 = __builtin_amdgcn_cvt_pk_f32_fp8(w, false);
                f32x2 hi2 = __builtin_amdgcn_cvt_pk_f32_fp8(w, true);
                b0 += lo2.x; b1 += lo2.y; b2 += hi2.x; b3 += hi2.y;
            }
        }
        a0 += __shfl_xor(a0, 16); a1 += __shfl_xor(a1, 16);
        a2 += __shfl_xor(a2, 16); a3 += __shfl_xor(a3, 16);
        b0 += __shfl_xor(b0, 16); b1 += __shfl_xor(b1, 16);
        b2 += __shfl_xor(b2, 16); b3 += __shfl_xor(b3, 16);

        float sc0 = 1.0f / fmaxf((float)c0, 1.0f);
        float sc1 = 1.0f / fmaxf((float)c1, 1.0f);
        float l0=-1e30f,l1=-1e30f,l2=-1e30f,l3=-1e30f;
        float m0=-1e30f,m1=-1e30f,m2=-1e30f,m3=-1e30f;
        if (dwl < 12) {
            l0 = a0 * sc0 + zs0.x;
            l1 = a1 * sc0 + zs0.y;
            l2 = a2 * sc0 + zs0.z;
            l3 = (dwl == 11) ? -1e30f : (a3 * sc0 + zs0.w);
            m0 = b0 * sc1 + zs1.x;
            m1 = b1 * sc1 + zs1.y;
            m2 = b2 * sc1 + zs1.z;
            m3 = (dwl == 11) ? -1e30f : (b3 * sc1 + zs1.w);
        }
        float mx0 = fmaxf(fmaxf(l0, l1), fmaxf(l2, l3));
        float mx1 = fmaxf(fmaxf(m0, m1), fmaxf(m2, m3));
#pragma unroll
        for (int off = 8; off >= 1; off >>= 1) {
            mx0 = fmaxf(mx0, __shfl_xor(mx0, off));
            mx1 = fmaxf(mx1, __shfl_xor(mx1, off));
        }
        float s0 = __expf(l0 - mx0) + __expf(l1 - mx0) +
                   __expf(l2 - mx0) + __expf(l3 - mx0);
        float s1 = __expf(m0 - mx1) + __expf(m1 - mx1) +
                   __expf(m2 - mx1) + __expf(m3 - mx1);
#pragma unroll
        for (int off = 8; off >= 1; off >>= 1) {
            s0 += __shfl_xor(s0, off);
            s1 += __shfl_xor(s1, off);
        }
        float lse0 = mx0 + __logf(s0);
        float lse1 = mx1 + __logf(s1);

        float va0 = (yi0 & 2) ? ((yi0 & 1) ? l3 : l2) : ((yi0 & 1) ? l1 : l0);
        float ly0 = __shfl(va0, h32 + (yi0 >> 2));
        float vb0 = (yi1 & 2) ? ((yi1 & 1) ? m3 : m2) : ((yi1 & 1) ? m1 : m0);
        float ly1 = __shfl(vb0, h32 + (yi1 >> 2));
        if (hl == 0) {
            num += (lse0 - ly0) + (v1 ? (lse1 - ly1) : 0.f);
            den += 1.f + (v1 ? 1.f : 0.f);
        }
    }

    if (hl == 0) {
        red[wave * 4 + half * 2]     = num;
        red[wave * 4 + half * 2 + 1] = den;
    }
    __syncthreads();
    if (tid == 0) {
        float n = 0.f, d = 0.f;
#pragma unroll
        for (int k = 0; k < 16; k += 2) { n += red[k]; d += red[k + 1]; }
        *(float2*)&partials[2 * blockIdx.x] = make_float2(n, d);
    }
}

// finalize: single block sums 2048 partial pairs (coalesced), writes loss
__global__ __launch_bounds__(256) void finalize_kernel(
    const float* __restrict__ partials, float* __restrict__ out)
{
    __shared__ float sn[4], sd[4];
    int tid = threadIdx.x;
    float n = 0.f, d = 0.f;
    for (int i = tid; i < LOSS_BLOCKS; i += 256) {
        float2 p = *(const float2*)&partials[2 * i];
        n += p.x; d += p.y;
    }
#pragma unroll
    for (int off = 32; off >= 1; off >>= 1) {
        n += __shfl_xor(n, off);
        d += __shfl_xor(d, off);
    }
    int wv = tid >> 6;
    if ((tid & 63) == 0) { sn[wv] = n; sd[wv] = d; }
    __syncthreads();
    if (tid == 0) {
        float N = (sn[0] + sn[1]) + (sn[2] + sn[3]);
        float D = (sd[0] + sd[1]) + (sd[2] + sd[3]);
        out[0] = N / fmaxf(D, 1.0f);
    }
}

// ---------------------------------------------------------------- launch
extern "C" void kernel_launch(void* const* d_in, const int* in_sizes, int n_in,
                              void* d_out, int out_size, void* d_ws, size_t ws_size,
                              hipStream_t stream) {
    const float* x   = (const float*)d_in[0];
    const int*   row = (const int*)d_in[1];
    const int*   col = (const int*)d_in[2];
    const int*   y   = (const int*)d_in[3];
    const int*   msk = (const int*)d_in[4];
    const float* w1n = (const float*)d_in[5];
    const float* b1n = (const float*)d_in[6];
    const float* w1s = (const float*)d_in[7];
    const float* b1s = (const float*)d_in[8];
    const float* w2n = (const float*)d_in[9];
    const float* b2n = (const float*)d_in[10];
    const float* w2s = (const float*)d_in[11];
    const float* b2s = (const float*)d_in[12];
    float* out = (float*)d_out;

    float* ws       = (float*)d_ws;
    float* partials = ws;                                 // 2*LOSS_BLOCKS floats
    int*   mcount   = (int*)(ws + 2 * LOSS_BLOCKS);       // 32-int pad region
    int*   cnt      = (int*)(ws + 2 * LOSS_BLOCKS + 32);  // 50048 ints
    unsigned short* bucket = (unsigned short*)(cnt + 50048);  // 3.2M ushorts
    unsigned* xq   = (unsigned*)(bucket + 3200000);       // NN*32 (fp8 x)
    unsigned* ab   = xq + (size_t)NN * 32;                // NN*128 dwords
    unsigned* znq  = ab + (size_t)NN * 128;               // NN*16 (fp8 logits, 64B rows)
    float* zsb     = (float*)(znq + (size_t)NN * 16);     // NN*48
    unsigned short* WB1 = (unsigned short*)(zsb + (size_t)NN * 48);  // 256*256
    unsigned short* WB2 = WB1 + 65536;                    // 96*256
    float* bias1   = (float*)(WB2 + 24576);               // 256
    int*   mlist   = (int*)(bias1 + 256);                 // 50048

    (void)hipMemsetAsync(mcount, 0, (32 + 50048) * sizeof(int), stream); // mcount+cnt

    prep_kernel<<<EDGE_BLOCKS + OTHER_BLOCKS, 256, 0, stream>>>(
        x, row, col, msk, w1n, w1s, b1n, b1s, w2n, w2s,
        cnt, bucket, xq, ab, WB1, WB2, bias1, znq, mcount, mlist);

    agg1<<<GS_BLOCKS, 256, 0, stream>>>(xq, cnt, bucket, ab);

    gemm12_fused<<<(NN + 63) / 64, 256, 0, stream>>>(
        (const unsigned short*)ab, WB1, WB2, bias1, b2n, b2s, znq, zsb);

    loss_kernel<<<LOSS_BLOCKS, 256, 0, stream>>>(
        znq, zsb, cnt, bucket, y, mcount, mlist, partials);

    finalize_kernel<<<1, 256, 0, stream>>>(partials, out);
}

// Round 14
// 208.609 us; speedup vs baseline: 1.0535x; 1.0535x over previous
//
#include <hip/hip_runtime.h>
#include <math.h>

#define NN 50000
#define EE 800000
#define DIN 128
#define HH 256
#define CC 47
#define LK2 264     // LDS row stride in bf16 (256 + 8 pad)
#define GS_BLOCKS 2048
#define LOSS_BLOCKS 2048
#define EDGE_CH 4096
#define EDGE_NCH ((EE + EDGE_CH - 1) / EDGE_CH)   // 196
#define EDGE_BLOCKS (EDGE_NCH * 8)                // 1568
#define OTHER_BLOCKS ((NN * 32 + 255) / 256)      // 6250

typedef short bf16x8 __attribute__((ext_vector_type(8)));
typedef float f32x4 __attribute__((ext_vector_type(4)));
typedef float f32x2 __attribute__((ext_vector_type(2)));

static __device__ __forceinline__ unsigned short f2bf(float f) {
    unsigned u = __float_as_uint(f);
    u = u + 0x7fff + ((u >> 16) & 1);
    return (unsigned short)(u >> 16);
}

// -- fused prep (R9 proven form). znq pad-zeroing removed: pad dwords are
// read by loss lanes dwl>=12 but their logits are pinned to -1e30 before
// any use, so their content is irrelevant (fp8 garbage never propagates).
__global__ __launch_bounds__(256) void prep_kernel(
    const float* __restrict__ x, const int* __restrict__ row,
    const int* __restrict__ col, const int* __restrict__ msk,
    const float* __restrict__ w1n, const float* __restrict__ w1s,
    const float* __restrict__ b1n, const float* __restrict__ b1s,
    const float* __restrict__ w2n, const float* __restrict__ w2s,
    int* __restrict__ cnt, unsigned short* __restrict__ bucket,
    unsigned* __restrict__ xq, unsigned* __restrict__ ab,
    unsigned short* __restrict__ WB1, unsigned short* __restrict__ WB2,
    float* __restrict__ bias1,
    int* __restrict__ mcount, int* __restrict__ mlist)
{
    if (blockIdx.x < EDGE_BLOCKS) {
        const int xcd = blockIdx.x & 7;
        const int base = (blockIdx.x >> 3) * EDGE_CH;
        for (int k = threadIdx.x; k < EDGE_CH; k += 256) {
            int e = base + k;
            if (e < EE) {
                int r = row[e];
                if ((r & 7) == xcd) {
                    int pos = atomicAdd(&cnt[r], 1);
                    if (pos < 64) bucket[r * 64 + pos] = (unsigned short)col[e];
                }
            }
        }
        return;
    }
    int t = (blockIdx.x - EDGE_BLOCKS) * 256 + threadIdx.x;
    if (t < NN) {
        int m = msk[t] ? 1 : 0;
        unsigned long long b = __ballot(m);
        int lane = threadIdx.x & 63;
        int prefix = __popcll(b & ((1ull << lane) - 1ull));
        int tot = __popcll(b);
        int base_ = 0;
        if (lane == 0 && tot) base_ = atomicAdd(mcount, tot);
        base_ = __shfl(base_, 0);
        if (m) mlist[base_ + prefix] = t;
    }
    if (t < NN * 32) {
        int i = t >> 5, c = t & 31;
        float4 v = *(const float4*)&x[(size_t)i * DIN + c * 4];
        int p = __builtin_amdgcn_cvt_pk_fp8_f32(v.x, v.y, 0, false);
        p = __builtin_amdgcn_cvt_pk_fp8_f32(v.z, v.w, p, true);
        xq[(size_t)i * 32 + c] = (unsigned)p;
        ab[(size_t)i * 128 + 64 + 2 * c]     = (unsigned)f2bf(v.x) | ((unsigned)f2bf(v.y) << 16);
        ab[(size_t)i * 128 + 64 + 2 * c + 1] = (unsigned)f2bf(v.z) | ((unsigned)f2bf(v.w) << 16);
    }
    if (t < 65536) {
        int k = t >> 8, n = t & 255;
        float v = (k < 128) ? w1n[k * HH + n] : w1s[(k - 128) * HH + n];
        WB1[n * 256 + k] = f2bf(v);
    } else if (t < 65536 + 24576) {
        int q = t - 65536;
        int k = q / 96, n = q % 96;
        float v;
        if (n < 48) v = (n < CC) ? w2n[k * CC + n] : 0.f;
        else { int m2 = n - 48; v = (m2 < CC) ? w2s[k * CC + m2] : 0.f; }
        WB2[n * 256 + k] = f2bf(v);
    } else if (t < 65536 + 24576 + 256) {
        int n = t - 65536 - 24576;
        bias1[n] = b1n[n] + b1s[n];
    }
}

// ----------------------------------------------- layer-1 gather (fp8 x)
// grid-stride: wave per node; half-wave per edge; single 64-slot batch.
__global__ __launch_bounds__(256) void agg1(const unsigned* __restrict__ xq,
                                            const int* __restrict__ cnt,
                                            const unsigned short* __restrict__ bucket,
                                            unsigned* __restrict__ ab) {
    int wave = threadIdx.x >> 6, lane = threadIdx.x & 63;
    const int h = lane >> 5, hl = lane & 31;
    const int W = gridDim.x * 4;
    for (int i = blockIdx.x * 4 + wave; i < NN; i += W) {
        int e = cnt[i];
        float dvs = fmaxf((float)e, 1.0f);
        if (e > 64) e = 64;
        float A0=0,A1=0,A2=0,A3=0, B0=0,B1=0,B2=0,B3=0;
        float C0=0,C1=0,C2=0,C3=0, D0=0,D1=0,D2=0,D3=0;
        if (e > 0) {
            int myidx = bucket[i * 64 + min(lane, e - 1)];
            int j = 0;
            for (; j + 16 <= e; j += 16) {
                int n0 = __shfl(myidx, j + h);
                int n1 = __shfl(myidx, j + 2 + h);
                int n2 = __shfl(myidx, j + 4 + h);
                int n3 = __shfl(myidx, j + 6 + h);
                int n4 = __shfl(myidx, j + 8 + h);
                int n5 = __shfl(myidx, j + 10 + h);
                int n6 = __shfl(myidx, j + 12 + h);
                int n7 = __shfl(myidx, j + 14 + h);
                unsigned u0 = xq[(size_t)n0 * 32 + hl];
                unsigned u1 = xq[(size_t)n1 * 32 + hl];
                unsigned u2 = xq[(size_t)n2 * 32 + hl];
                unsigned u3 = xq[(size_t)n3 * 32 + hl];
                unsigned u4 = xq[(size_t)n4 * 32 + hl];
                unsigned u5 = xq[(size_t)n5 * 32 + hl];
                unsigned u6 = xq[(size_t)n6 * 32 + hl];
                unsigned u7 = xq[(size_t)n7 * 32 + hl];
                f32x2 l0 = __builtin_amdgcn_cvt_pk_f32_fp8(u0, false);
                f32x2 h0 = __builtin_amdgcn_cvt_pk_f32_fp8(u0, true);
                f32x2 l1 = __builtin_amdgcn_cvt_pk_f32_fp8(u1, false);
                f32x2 h1 = __builtin_amdgcn_cvt_pk_f32_fp8(u1, true);
                f32x2 l2 = __builtin_amdgcn_cvt_pk_f32_fp8(u2, false);
                f32x2 h2 = __builtin_amdgcn_cvt_pk_f32_fp8(u2, true);
                f32x2 l3 = __builtin_amdgcn_cvt_pk_f32_fp8(u3, false);
                f32x2 h3 = __builtin_amdgcn_cvt_pk_f32_fp8(u3, true);
                A0 += l0.x; A1 += l0.y; A2 += h0.x; A3 += h0.y;
                B0 += l1.x; B1 += l1.y; B2 += h1.x; B3 += h1.y;
                C0 += l2.x; C1 += l2.y; C2 += h2.x; C3 += h2.y;
                D0 += l3.x; D1 += l3.y; D2 += h3.x; D3 += h3.y;
                f32x2 l4 = __builtin_amdgcn_cvt_pk_f32_fp8(u4, false);
                f32x2 h4 = __builtin_amdgcn_cvt_pk_f32_fp8(u4, true);
                f32x2 l5 = __builtin_amdgcn_cvt_pk_f32_fp8(u5, false);
                f32x2 h5 = __builtin_amdgcn_cvt_pk_f32_fp8(u5, true);
                f32x2 l6 = __builtin_amdgcn_cvt_pk_f32_fp8(u6, false);
                f32x2 h6 = __builtin_amdgcn_cvt_pk_f32_fp8(u6, true);
                f32x2 l7 = __builtin_amdgcn_cvt_pk_f32_fp8(u7, false);
                f32x2 h7 = __builtin_amdgcn_cvt_pk_f32_fp8(u7, true);
                A0 += l4.x; A1 += l4.y; A2 += h4.x; A3 += h4.y;
                B0 += l5.x; B1 += l5.y; B2 += h5.x; B3 += h5.y;
                C0 += l6.x; C1 += l6.y; C2 += h6.x; C3 += h6.y;
                D0 += l7.x; D1 += l7.y; D2 += h7.x; D3 += h7.y;
            }
            for (; j + 8 <= e; j += 8) {
                int n0 = __shfl(myidx, j + h);
                int n1 = __shfl(myidx, j + 2 + h);
                int n2 = __shfl(myidx, j + 4 + h);
                int n3 = __shfl(myidx, j + 6 + h);
                unsigned u0 = xq[(size_t)n0 * 32 + hl];
                unsigned u1 = xq[(size_t)n1 * 32 + hl];
                unsigned u2 = xq[(size_t)n2 * 32 + hl];
                unsigned u3 = xq[(size_t)n3 * 32 + hl];
                f32x2 l0 = __builtin_amdgcn_cvt_pk_f32_fp8(u0, false);
                f32x2 h0 = __builtin_amdgcn_cvt_pk_f32_fp8(u0, true);
                f32x2 l1 = __builtin_amdgcn_cvt_pk_f32_fp8(u1, false);
                f32x2 h1 = __builtin_amdgcn_cvt_pk_f32_fp8(u1, true);
                f32x2 l2 = __builtin_amdgcn_cvt_pk_f32_fp8(u2, false);
                f32x2 h2 = __builtin_amdgcn_cvt_pk_f32_fp8(u2, true);
                f32x2 l3 = __builtin_amdgcn_cvt_pk_f32_fp8(u3, false);
                f32x2 h3 = __builtin_amdgcn_cvt_pk_f32_fp8(u3, true);
                A0 += l0.x; A1 += l0.y; A2 += h0.x; A3 += h0.y;
                B0 += l1.x; B1 += l1.y; B2 += h1.x; B3 += h1.y;
                C0 += l2.x; C1 += l2.y; C2 += h2.x; C3 += h2.y;
                D0 += l3.x; D1 += l3.y; D2 += h3.x; D3 += h3.y;
            }
            for (; j < e; j += 2) {
                int src = j + h;
                int n = __shfl(myidx, min(src, e - 1));
                unsigned u = xq[(size_t)n * 32 + hl];
                if (src >= e) u = 0u;
                f32x2 lo = __builtin_amdgcn_cvt_pk_f32_fp8(u, false);
                f32x2 hi = __builtin_amdgcn_cvt_pk_f32_fp8(u, true);
                A0 += lo.x; A1 += lo.y; A2 += hi.x; A3 += hi.y;
            }
        }
        float s0 = (A0 + B0) + (C0 + D0);
        float s1 = (A1 + B1) + (C1 + D1);
        float s2 = (A2 + B2) + (C2 + D2);
        float s3 = (A3 + B3) + (C3 + D3);
        s0 += __shfl_xor(s0, 32); s1 += __shfl_xor(s1, 32);
        s2 += __shfl_xor(s2, 32); s3 += __shfl_xor(s3, 32);
        if (h == 0) {
            float sc = 1.0f / dvs;
            unsigned d0 = (unsigned)f2bf(s0 * sc) | ((unsigned)f2bf(s1 * sc) << 16);
            unsigned d1 = (unsigned)f2bf(s2 * sc) | ((unsigned)f2bf(s3 * sc) << 16);
            *(uint2*)&ab[(size_t)i * 128 + 2 * hl] = make_uint2(d0, d1);
        }
    }
}

// ------------------- FUSED layer-1 + layer-2 GEMM (R9 proven version):
// 64 rows/block; A in regs; sB double-buffered with register prefetch;
// 1 barrier/phase. LDS 67.6KB -> 2 blocks/CU.
__global__ __launch_bounds__(256) void gemm12_fused(
    const unsigned short* __restrict__ AB,
    const unsigned short* __restrict__ WB1, const unsigned short* __restrict__ WB2,
    const float* __restrict__ bias1,
    const float* __restrict__ b2n, const float* __restrict__ b2s,
    unsigned* __restrict__ znq, float* __restrict__ zsb)
{
    __shared__ unsigned short sB[2][32 * LK2];
    __shared__ unsigned short sH[64 * LK2];
    const int tid = threadIdx.x;
    const int i0 = blockIdx.x * 64;
    const int wv = tid >> 6, lane = tid & 63;
    const int g = lane >> 4, l16 = lane & 15;
    const int m0 = wv * 16;

    bf16x8 areg[8];
    {
        const int arow = i0 + m0 + l16;
#pragma unroll
        for (int ks = 0; ks < 8; ++ks) {
            bf16x8 v = {};
            if (arow < NN) v = *(const bf16x8*)&AB[(size_t)arow * 256 + g * 8 + 32 * ks];
            areg[ks] = v;
        }
    }

    int4 breg[4];
#pragma unroll
    for (int l = 0; l < 4; ++l) {
        int c = tid + l * 256;
        int r = c >> 5, c8 = (c & 31) * 8;
        breg[l] = *(const int4*)&WB1[(size_t)r * 256 + c8];
    }
#pragma unroll
    for (int l = 0; l < 4; ++l) {
        int c = tid + l * 256;
        int r = c >> 5, c8 = (c & 31) * 8;
        *(int4*)&sB[0][r * LK2 + c8] = breg[l];
    }
    __syncthreads();

    for (int n0 = 0; n0 < 8; ++n0) {
        const int buf = n0 & 1;
        {
            const unsigned short* src = (n0 < 7) ? &WB1[(size_t)((n0 + 1) * 32) * 256]
                                                 : &WB2[0];
#pragma unroll
            for (int l = 0; l < 4; ++l) {
                int c = tid + l * 256;
                int r = c >> 5, c8 = (c & 31) * 8;
                breg[l] = *(const int4*)&src[(size_t)r * 256 + c8];
            }
        }
#pragma unroll
        for (int cg = 0; cg < 2; ++cg) {
            f32x4 p0 = {}, p1 = {}, p2 = {}, p3 = {};
            const unsigned short* br = &sB[buf][(cg * 16 + l16) * LK2 + g * 8];
            p0 = __builtin_amdgcn_mfma_f32_16x16x32_bf16(areg[0], *(const bf16x8*)(br +   0), p0, 0, 0, 0);
            p1 = __builtin_amdgcn_mfma_f32_16x16x32_bf16(areg[1], *(const bf16x8*)(br +  32), p1, 0, 0, 0);
            p2 = __builtin_amdgcn_mfma_f32_16x16x32_bf16(areg[2], *(const bf16x8*)(br +  64), p2, 0, 0, 0);
            p3 = __builtin_amdgcn_mfma_f32_16x16x32_bf16(areg[3], *(const bf16x8*)(br +  96), p3, 0, 0, 0);
            p0 = __builtin_amdgcn_mfma_f32_16x16x32_bf16(areg[4], *(const bf16x8*)(br + 128), p0, 0, 0, 0);
            p1 = __builtin_amdgcn_mfma_f32_16x16x32_bf16(areg[5], *(const bf16x8*)(br + 160), p1, 0, 0, 0);
            p2 = __builtin_amdgcn_mfma_f32_16x16x32_bf16(areg[6], *(const bf16x8*)(br + 192), p2, 0, 0, 0);
            p3 = __builtin_amdgcn_mfma_f32_16x16x32_bf16(areg[7], *(const bf16x8*)(br + 224), p3, 0, 0, 0);
            f32x4 acc = (p0 + p1) + (p2 + p3);
            int colh = n0 * 32 + cg * 16 + l16;
            float bi = bias1[colh];
#pragma unroll
            for (int r = 0; r < 4; ++r)
                sH[(m0 + g * 4 + r) * LK2 + colh] = f2bf(fmaxf(acc[r] + bi, 0.f));
        }
#pragma unroll
        for (int l = 0; l < 4; ++l) {
            int c = tid + l * 256;
            int r = c >> 5, c8 = (c & 31) * 8;
            *(int4*)&sB[buf ^ 1][r * LK2 + c8] = breg[l];
        }
        __syncthreads();
    }

    for (int m = 0; m < 3; ++m) {
        const int buf = m & 1;
        if (m < 2) {
#pragma unroll
            for (int l = 0; l < 4; ++l) {
                int c = tid + l * 256;
                int r = c >> 5, c8 = (c & 31) * 8;
                breg[l] = *(const int4*)&WB2[(size_t)((m + 1) * 32 + r) * 256 + c8];
            }
        }
#pragma unroll
        for (int cg = 0; cg < 2; ++cg) {
            f32x4 p0 = {}, p1 = {}, p2 = {}, p3 = {};
            const unsigned short* ar = &sH[(m0 + l16) * LK2 + g * 8];
            const unsigned short* br = &sB[buf][(cg * 16 + l16) * LK2 + g * 8];
            p0 = __builtin_amdgcn_mfma_f32_16x16x32_bf16(*(const bf16x8*)(ar +   0), *(const bf16x8*)(br +   0), p0, 0, 0, 0);
            p1 = __builtin_amdgcn_mfma_f32_16x16x32_bf16(*(const bf16x8*)(ar +  32), *(const bf16x8*)(br +  32), p1, 0, 0, 0);
            p2 = __builtin_amdgcn_mfma_f32_16x16x32_bf16(*(const bf16x8*)(ar +  64), *(const bf16x8*)(br +  64), p2, 0, 0, 0);
            p3 = __builtin_amdgcn_mfma_f32_16x16x32_bf16(*(const bf16x8*)(ar +  96), *(const bf16x8*)(br +  96), p3, 0, 0, 0);
            p0 = __builtin_amdgcn_mfma_f32_16x16x32_bf16(*(const bf16x8*)(ar + 128), *(const bf16x8*)(br + 128), p0, 0, 0, 0);
            p1 = __builtin_amdgcn_mfma_f32_16x16x32_bf16(*(const bf16x8*)(ar + 160), *(const bf16x8*)(br + 160), p1, 0, 0, 0);
            p2 = __builtin_amdgcn_mfma_f32_16x16x32_bf16(*(const bf16x8*)(ar + 192), *(const bf16x8*)(br + 192), p2, 0, 0, 0);
            p3 = __builtin_amdgcn_mfma_f32_16x16x32_bf16(*(const bf16x8*)(ar + 224), *(const bf16x8*)(br + 224), p3, 0, 0, 0);
            f32x4 acc = (p0 + p1) + (p2 + p3);
            int c = m * 32 + cg * 16 + l16;
            if (c < 48) {
#pragma unroll
                for (int r = 0; r < 4; ++r) {
                    int gi = i0 + m0 + g * 4 + r;
                    float v = acc[r];
                    float v1 = __shfl_down(v, 1);
                    float v2 = __shfl_down(v, 2);
                    float v3 = __shfl_down(v, 3);
                    if (((l16 & 3) == 0) && gi < NN) {
                        int pk = __builtin_amdgcn_cvt_pk_fp8_f32(v, v1, 0, false);
                        pk = __builtin_amdgcn_cvt_pk_fp8_f32(v2, v3, pk, true);
                        znq[(size_t)gi * 16 + (c >> 2)] = (unsigned)pk;
                    }
                }
            } else {
                int cz = c - 48;
                float bias = (cz < CC) ? (b2n[cz] + b2s[cz]) : 0.f;
#pragma unroll
                for (int r = 0; r < 4; ++r) {
                    int gi = i0 + m0 + g * 4 + r;
                    if (gi < NN) zsb[(size_t)gi * 48 + cz] = acc[r] + bias;
                }
            }
        }
        if (m < 2) {
#pragma unroll
            for (int l = 0; l < 4; ++l) {
                int c2 = tid + l * 256;
                int r = c2 >> 5, c8 = (c2 & 31) * 8;
                *(int4*)&sB[buf ^ 1][r * LK2 + c8] = breg[l];
            }
        }
        __syncthreads();
    }
}

// --------------- masked loss: mlist, fp8 znq, 2 nodes per half-wave concurrent,
// per-block partials via plain stores (no same-address atomics)
__global__ __launch_bounds__(256) void loss_kernel(
    const unsigned* __restrict__ znq, const float* __restrict__ zsb,
    const int* __restrict__ cnt, const unsigned short* __restrict__ bucket,
    const int* __restrict__ y, const int* __restrict__ mcount,
    const int* __restrict__ mlist, float* __restrict__ partials)
{
    __shared__ float red[16];
    const int tid = threadIdx.x;
    const int wave = tid >> 6, lane = tid & 63;
    const int half = lane >> 5, hl = lane & 31;
    const int h32 = lane & 32;
    const int eg = hl >> 4, dwl = hl & 15;
    const int HW = gridDim.x * 8;
    const int M = mcount[0];
    float num = 0.f, den = 0.f;

    for (int pa = ((blockIdx.x * 4 + wave) * 2 + half) * 2; pa < M; pa += 2 * HW) {
        int i0 = mlist[pa];
        bool v1 = (pa + 1 < M);
        int i1 = v1 ? mlist[pa + 1] : i0;
        int c0 = cnt[i0], c1 = cnt[i1];
        int e0 = min(c0, 64), e1 = min(c1, 64);
        int yi0 = y[i0], yi1 = y[i1];
        int mi0 = bucket[(size_t)i0 * 64 + min(hl, max(e0 - 1, 0))];
        int mi1 = bucket[(size_t)i1 * 64 + min(hl, max(e1 - 1, 0))];
        int dwm = min(dwl, 11);
        float4 zs0 = *(const float4*)&zsb[(size_t)i0 * 48 + 4 * dwm];
        float4 zs1 = *(const float4*)&zsb[(size_t)i1 * 48 + 4 * dwm];

        unsigned ua[16], ub[16];
#pragma unroll
        for (int q = 0; q < 16; ++q) {
            int n = __shfl(mi0, h32 + 2 * q + eg);
            ua[q] = znq[(size_t)n * 16 + dwl];
        }
#pragma unroll
        for (int q = 0; q < 16; ++q) {
            int n = __shfl(mi1, h32 + 2 * q + eg);
            ub[q] = znq[(size_t)n * 16 + dwl];
        }
        float a0=0.f,a1=0.f,a2=0.f,a3=0.f, b0=0.f,b1=0.f,b2=0.f,b3=0.f;
#pragma unroll
        for (int q = 0; q < 16; ++q) {
            int s = 2 * q + eg;
            unsigned u = (s < e0) ? ua[q] : 0u;
            f32x2 lo = __builtin_amdgcn_cvt_pk_f32_fp8(u, false);
            f32x2 hi = __builtin_amdgcn_cvt_pk_f32_fp8(u, true);
            a0 += lo.x; a1 += lo.y; a2 += hi.x; a3 += hi.y;
            unsigned w = (s < e1) ? ub[q] : 0u;
            f32x2 lo2 = __builtin_amdgcn_cvt_pk_f32_fp8(w, false);
            f32x2 hi2 = __builtin_amdgcn_cvt_pk_f32_fp8(w, true);
            b0 += lo2.x; b1 += lo2.y; b2 += hi2.x; b3 += hi2.y;
        }
        if (e0 > 32 || e1 > 32) {
            int mj0 = bucket[(size_t)i0 * 64 + min(32 + hl, max(e0 - 1, 0))];
            int mj1 = bucket[(size_t)i1 * 64 + min(32 + hl, max(e1 - 1, 0))];
            unsigned va[16], vb[16];
#pragma unroll
            for (int q = 0; q < 16; ++q) {
                int n = __shfl(mj0, h32 + 2 * q + eg);
                va[q] = znq[(size_t)n * 16 + dwl];
            }
#pragma unroll
            for (int q = 0; q < 16; ++q) {
                int n = __shfl(mj1, h32 + 2 * q + eg);
                vb[q] = znq[(size_t)n * 16 + dwl];
            }
#pragma unroll
            for (int q = 0; q < 16; ++q) {
                int s = 32 + 2 * q + eg;
                unsigned u = (s < e0) ? va[q] : 0u;
                f32x2 lo = __builtin_amdgcn_cvt_pk_f32_fp8(u, false);
                f32x2 hi = __builtin_amdgcn_cvt_pk_f32_fp8(u, true);
                a0 += lo.x; a1 += lo.y; a2 += hi.x; a3 += hi.y;
                unsigned w = (s < e1) ? vb[q] : 0u;
                f32x2 lo2 = __builtin_amdgcn_cvt_pk_f32_fp8(w, false);
                f32x2 hi2 = __builtin_amdgcn_cvt_pk_f32_fp8(w, true);
                b0 += lo2.x; b1 += lo2.y; b2 += hi2.x; b3 += hi2.y;
            }
        }
        a0 += __shfl_xor(a0, 16); a1 += __shfl_xor(a1, 16);
        a2 += __shfl_xor(a2, 16); a3 += __shfl_xor(a3, 16);
        b0 += __shfl_xor(b0, 16); b1 += __shfl_xor(b1, 16);
        b2 += __shfl_xor(b2, 16); b3 += __shfl_xor(b3, 16);

        float sc0 = 1.0f / fmaxf((float)c0, 1.0f);
        float sc1 = 1.0f / fmaxf((float)c1, 1.0f);
        float l0=-1e30f,l1=-1e30f,l2=-1e30f,l3=-1e30f;
        float m0=-1e30f,m1=-1e30f,m2=-1e30f,m3=-1e30f;
        if (dwl < 12) {
            l0 = a0 * sc0 + zs0.x;
            l1 = a1 * sc0 + zs0.y;
            l2 = a2 * sc0 + zs0.z;
            l3 = (dwl == 11) ? -1e30f : (a3 * sc0 + zs0.w);
            m0 = b0 * sc1 + zs1.x;
            m1 = b1 * sc1 + zs1.y;
            m2 = b2 * sc1 + zs1.z;
            m3 = (dwl == 11) ? -1e30f : (b3 * sc1 + zs1.w);
        }
        float mx0 = fmaxf(fmaxf(l0, l1), fmaxf(l2, l3));
        float mx1 = fmaxf(fmaxf(m0, m1), fmaxf(m2, m3));
#pragma unroll
        for (int off = 8; off >= 1; off >>= 1) {
            mx0 = fmaxf(mx0, __shfl_xor(mx0, off));
            mx1 = fmaxf(mx1, __shfl_xor(mx1, off));
        }
        float s0 = __expf(l0 - mx0) + __expf(l1 - mx0) +
                   __expf(l2 - mx0) + __expf(l3 - mx0);
        float s1 = __expf(m0 - mx1) + __expf(m1 - mx1) +
                   __expf(m2 - mx1) + __expf(m3 - mx1);
#pragma unroll
        for (int off = 8; off >= 1; off >>= 1) {
            s0 += __shfl_xor(s0, off);
            s1 += __shfl_xor(s1, off);
        }
        float lse0 = mx0 + __logf(s0);
        float lse1 = mx1 + __logf(s1);

        float va0 = (yi0 & 2) ? ((yi0 & 1) ? l3 : l2) : ((yi0 & 1) ? l1 : l0);
        float ly0 = __shfl(va0, h32 + (yi0 >> 2));
        float vb0 = (yi1 & 2) ? ((yi1 & 1) ? m3 : m2) : ((yi1 & 1) ? m1 : m0);
        float ly1 = __shfl(vb0, h32 + (yi1 >> 2));
        if (hl == 0) {
            num += (lse0 - ly0) + (v1 ? (lse1 - ly1) : 0.f);
            den += 1.f + (v1 ? 1.f : 0.f);
        }
    }

    if (hl == 0) {
        red[wave * 4 + half * 2]     = num;
        red[wave * 4 + half * 2 + 1] = den;
    }
    __syncthreads();
    if (tid == 0) {
        float n = 0.f, d = 0.f;
#pragma unroll
        for (int k = 0; k < 16; k += 2) { n += red[k]; d += red[k + 1]; }
        *(float2*)&partials[2 * blockIdx.x] = make_float2(n, d);
    }
}

// finalize: single block sums 2048 partial pairs (coalesced), writes loss
__global__ __launch_bounds__(256) void finalize_kernel(
    const float* __restrict__ partials, float* __restrict__ out)
{
    __shared__ float sn[4], sd[4];
    int tid = threadIdx.x;
    float n = 0.f, d = 0.f;
    for (int i = tid; i < LOSS_BLOCKS; i += 256) {
        float2 p = *(const float2*)&partials[2 * i];
        n += p.x; d += p.y;
    }
#pragma unroll
    for (int off = 32; off >= 1; off >>= 1) {
        n += __shfl_xor(n, off);
        d += __shfl_xor(d, off);
    }
    int wv = tid >> 6;
    if ((tid & 63) == 0) { sn[wv] = n; sd[wv] = d; }
    __syncthreads();
    if (tid == 0) {
        float N = (sn[0] + sn[1]) + (sn[2] + sn[3]);
        float D = (sd[0] + sd[1]) + (sd[2] + sd[3]);
        out[0] = N / fmaxf(D, 1.0f);
    }
}

// ---------------------------------------------------------------- launch
extern "C" void kernel_launch(void* const* d_in, const int* in_sizes, int n_in,
                              void* d_out, int out_size, void* d_ws, size_t ws_size,
                              hipStream_t stream) {
    const float* x   = (const float*)d_in[0];
    const int*   row = (const int*)d_in[1];
    const int*   col = (const int*)d_in[2];
    const int*   y   = (const int*)d_in[3];
    const int*   msk = (const int*)d_in[4];
    const float* w1n = (const float*)d_in[5];
    const float* b1n = (const float*)d_in[6];
    const float* w1s = (const float*)d_in[7];
    const float* b1s = (const float*)d_in[8];
    const float* w2n = (const float*)d_in[9];
    const float* b2n = (const float*)d_in[10];
    const float* w2s = (const float*)d_in[11];
    const float* b2s = (const float*)d_in[12];
    float* out = (float*)d_out;

    float* ws       = (float*)d_ws;
    float* partials = ws;                                 // 2*LOSS_BLOCKS floats
    int*   mcount   = (int*)(ws + 2 * LOSS_BLOCKS);       // 32-int pad region
    int*   cnt      = (int*)(ws + 2 * LOSS_BLOCKS + 32);  // 50048 ints
    unsigned short* bucket = (unsigned short*)(cnt + 50048);  // 3.2M ushorts
    unsigned* xq   = (unsigned*)(bucket + 3200000);       // NN*32 (fp8 x)
    unsigned* ab   = xq + (size_t)NN * 32;                // NN*128 dwords
    unsigned* znq  = ab + (size_t)NN * 128;               // NN*16 (fp8 logits, 64B rows)
    float* zsb     = (float*)(znq + (size_t)NN * 16);     // NN*48
    unsigned short* WB1 = (unsigned short*)(zsb + (size_t)NN * 48);  // 256*256
    unsigned short* WB2 = WB1 + 65536;                    // 96*256
    float* bias1   = (float*)(WB2 + 24576);               // 256
    int*   mlist   = (int*)(bias1 + 256);                 // 50048

    (void)hipMemsetAsync(mcount, 0, (32 + 50048) * sizeof(int), stream); // mcount+cnt

    prep_kernel<<<EDGE_BLOCKS + OTHER_BLOCKS, 256, 0, stream>>>(
        x, row, col, msk, w1n, w1s, b1n, b1s, w2n, w2s,
        cnt, bucket, xq, ab, WB1, WB2, bias1, mcount, mlist);

    agg1<<<GS_BLOCKS, 256, 0, stream>>>(xq, cnt, bucket, ab);

    gemm12_fused<<<(NN + 63) / 64, 256, 0, stream>>>(
        (const unsigned short*)ab, WB1, WB2, bias1, b2n, b2s, znq, zsb);

    loss_kernel<<<LOSS_BLOCKS, 256, 0, stream>>>(
        znq, zsb, cnt, bucket, y, mcount, mlist, partials);

    finalize_kernel<<<1, 256, 0, stream>>>(partials, out);
}